// Round 11
// baseline (200.542 us; speedup 1.0000x reference)
//
#include <hip/hip_runtime.h>

typedef __attribute__((ext_vector_type(8))) short bf16x8;
typedef __attribute__((ext_vector_type(4))) float f32x4;
typedef unsigned short ushort_t;
typedef unsigned int uint_t;

constexpr int PEP = 15;   // peptide length
constexpr int D   = 64;   // feature dim
constexpr int L   = 34;   // mhc length (stage-1 contraction)
constexpr int OC  = 128;  // output channels
constexpr int KS  = 9;    // kernel size
constexpr int TO  = 7;    // output positions
constexpr int OK  = OC * KS;      // 1152 stage-1 rows
constexpr int MTG = OK / 16;      // 72 global M-tiles
constexpr int NCHB = 4;           // chunks per block (grid-split 2x)
constexpr int CHO = 16;           // o per chunk
constexpr int MT_CH = 9;          // M-tiles per chunk (144 rows)
// LDS: CTb bf16-hi [144 rows][144 B] (row = o_local*9+k, d*2 bytes within row)
//      pepH/pepL bf16 [24 rows][144 B] (rows >=15 zero-padded)
constexpr int CTR = 144;                        // CTb row stride bytes
constexpr int PPR = 144;                        // pep plane row stride bytes
constexpr int PEPH_OFF = 144 * CTR;             // 20736
constexpr int PEPL_OFF = PEPH_OFF + 24 * PPR;   // 24192
constexpr int SMEM_BYTES = PEPL_OFF + 24 * PPR; // 27648
// wprep layout (294912 B, unchanged from r8):
//   [0,36864) hi frags k=0..31: mt*512+lane*8+i ; [36864,73728) lo frags
//   f32 tail at ushort 73728: mt*512+lane*8+j*2+c -> W[(mt*16+(lane>>4)*4+j)*L+32+c]
constexpr int WP_FRAG = 36864;
constexpr int WP_TAILF = 36864;

__device__ __forceinline__ ushort_t f2bf(float v) {
    uint_t u = __float_as_uint(v);
    return (ushort_t)((u + 0x7fffu + ((u >> 16) & 1u)) >> 16);   // RTNE
}
__device__ __forceinline__ float bf2f(ushort_t h) {
    return __uint_as_float(((uint_t)h) << 16);
}
__device__ __forceinline__ uint_t cvt_pk_bf16(float a, float b) {
    uint_t r;
    asm("v_cvt_pk_bf16_f32 %0, %1, %2" : "=v"(r) : "v"(a), "v"(b));
    return r;   // lo = bf16(a), hi = bf16(b)
}

// Pre-kernel: W -> {hi,lo bf16 frags l=0..31} + {exact f32 tail l=32,33}.
__global__ void wprep_kernel(const float* __restrict__ W, ushort_t* __restrict__ wp) {
    int x = blockIdx.x * 256 + threadIdx.x;
    if (x < 2 * WP_FRAG) {
        int sp = x / WP_FRAG;
        int r  = x % WP_FRAG;
        int i  = r & 7;
        int ln = (r >> 3) & 63;
        int mt = r >> 9;
        int ok = mt * 16 + (ln & 15);
        int l  = (ln >> 4) * 8 + i;
        float v = W[ok * L + l];
        ushort_t hi = f2bf(v);
        wp[x] = sp ? f2bf(v - bf2f(hi)) : hi;
    } else if (x < 2 * WP_FRAG + WP_TAILF) {
        int y  = x - 2 * WP_FRAG;
        int c  = y & 1;
        int j  = (y >> 1) & 3;
        int ln = (y >> 3) & 63;
        int mt = y >> 9;
        int row = mt * 16 + (ln >> 4) * 4 + j;
        ((float*)(wp + 2 * WP_FRAG))[y] = W[row * L + 32 + c];
    }
}

// out[n,o,t] initialized to bias[o]; stage-2 partials atomically accumulate.
__global__ void oinit_kernel(const float* __restrict__ bias, float* __restrict__ out, int total) {
    int i = blockIdx.x * 256 + threadIdx.x;
    if (i < total) out[i] = bias[(i % (OC * TO)) / TO];
}

// Grid (bs, 2). Per chunk (16 o): stage-1 MFMA (3-product K=0..31 + exact f32
// tail) -> relu -> CTb (bf16-hi). BAR1. Stage-2 MFMA: D[t,o] += p[t+k]*Khi,
// A=pep hi/lo (LDS-staged), B=CTb direct; waves split k {3,2,2,2}; partials
// via unsafeAtomicAdd into bias-preinit out. BAR2 (CTb WAR). No butterfly,
// no so, no epilogue.
__global__ __launch_bounds__(256, 4) void iconv_mfma(
    const float* __restrict__ pep,
    const float* __restrict__ mhc,
    const ushort_t* __restrict__ wp,
    float* __restrict__ out)
{
    __shared__ __align__(16) char smem[SMEM_BYTES];
    const int n    = blockIdx.x;
    const int c0   = blockIdx.y * NCHB;
    const int tid  = threadIdx.x;
    const int lane = tid & 63;
    const int w    = tid >> 6;

    // m rows 32,33 exact f32 (stage-1 K-tail), per nt
    float m32v[4], m33v[4];
    {
        const float* mb = mhc + (size_t)n * L * D;
        #pragma unroll
        for (int nt = 0; nt < 4; ++nt) {
            int d = (lane & 15) + 16 * nt;
            m32v[nt] = mb[32 * D + d];
            m33v[nt] = mb[33 * D + d];
        }
    }

    // Prologue A: m^T (l=0..31) hi/lo bf16 XOR-swizzled at [0,16384) (one-time)
    {
        const float* mp = mhc + (size_t)n * L * D + lane;
        #pragma unroll
        for (int j = 0; j < 8; ++j) {
            int l = w + 4 * j;
            float v = mp[l * D];
            ushort_t hi = f2bf(v);
            ushort_t lo = f2bf(v - bf2f(hi));
            int byte = (lane * 128 + l * 2) ^ ((lane & 7) << 4);
            *(ushort_t*)(smem + byte)        = hi;
            *(ushort_t*)(smem + 8192 + byte) = lo;
        }
    }
    // Prologue B: pep rows 0..23 (>=15 zero) hi/lo bf16 planes (144B rows)
    {
        const float* pp = pep + (size_t)n * PEP * D + lane;
        #pragma unroll
        for (int j = 0; j < 6; ++j) {
            int r = w + 4 * j;
            float v = (r < PEP) ? pp[r * D] : 0.0f;
            ushort_t hi = f2bf(v);
            ushort_t lo = f2bf(v - bf2f(hi));
            int byte = r * PPR + lane * 2;
            *(ushort_t*)(smem + PEPH_OFF + byte) = hi;
            *(ushort_t*)(smem + PEPL_OFF + byte) = lo;
        }
    }
    __syncthreads();

    // stage-1 B-fragments (m): [nt][hi/lo]
    bf16x8 bf[4][2];
    #pragma unroll
    for (int nt = 0; nt < 4; ++nt) {
        int d = (lane & 15) + 16 * nt;
        int l0 = (lane >> 4) * 8;
        int byte = (d * 128 + l0 * 2) ^ ((d & 7) << 4);
        bf[nt][0] = *(const bf16x8*)(smem + byte);
        bf[nt][1] = *(const bf16x8*)(smem + 8192 + byte);
    }
    __syncthreads();   // mT dead; CTb may overwrite [0,20736)

    const float* wtail = (const float*)(wp + 2 * WP_FRAG);

    auto do_tile = [&](int cg, int mtl) {
        int mtG = cg * MT_CH + mtl;
        const ushort_t* base = wp + mtG * 512 + lane * 8;
        bf16x8 ah = *(const bf16x8*)(base);
        bf16x8 al = *(const bf16x8*)(base + WP_FRAG);
        const float4* tb = (const float4*)(wtail + (size_t)(mtG * 64 + lane) * 8);
        float4 ft0 = tb[0];
        float4 ft1 = tb[1];

        f32x4 acc[4];
        #pragma unroll
        for (int nt = 0; nt < 4; ++nt) acc[nt] = (f32x4){0.f, 0.f, 0.f, 0.f};
        #pragma unroll
        for (int nt = 0; nt < 4; ++nt) {
            acc[nt] = __builtin_amdgcn_mfma_f32_16x16x32_bf16(ah, bf[nt][0], acc[nt], 0, 0, 0);
            acc[nt] = __builtin_amdgcn_mfma_f32_16x16x32_bf16(ah, bf[nt][1], acc[nt], 0, 0, 0);
            acc[nt] = __builtin_amdgcn_mfma_f32_16x16x32_bf16(al, bf[nt][0], acc[nt], 0, 0, 0);
        }
        #pragma unroll
        for (int nt = 0; nt < 4; ++nt) {   // exact K-tail l=32,33
            acc[nt][0] = fmaf(ft0.x, m32v[nt], fmaf(ft0.y, m33v[nt], acc[nt][0]));
            acc[nt][1] = fmaf(ft0.z, m32v[nt], fmaf(ft0.w, m33v[nt], acc[nt][1]));
            acc[nt][2] = fmaf(ft1.x, m32v[nt], fmaf(ft1.y, m33v[nt], acc[nt][2]));
            acc[nt][3] = fmaf(ft1.z, m32v[nt], fmaf(ft1.w, m33v[nt], acc[nt][3]));
        }

        int r0 = mtl * 16 + (lane >> 4) * 4;
        #pragma unroll
        for (int nt = 0; nt < 4; ++nt) {   // relu -> bf16-hi -> CTb[row][d]
            int bb = ((lane & 15) + 16 * nt) * 2;
            uint_t w01 = cvt_pk_bf16(fmaxf(acc[nt][0], 0.f), fmaxf(acc[nt][1], 0.f));
            uint_t w23 = cvt_pk_bf16(fmaxf(acc[nt][2], 0.f), fmaxf(acc[nt][3], 0.f));
            *(ushort_t*)(smem + (r0 + 0) * CTR + bb) = (ushort_t)(w01 & 0xffffu);
            *(ushort_t*)(smem + (r0 + 1) * CTR + bb) = (ushort_t)(w01 >> 16);
            *(ushort_t*)(smem + (r0 + 2) * CTR + bb) = (ushort_t)(w23 & 0xffffu);
            *(ushort_t*)(smem + (r0 + 3) * CTR + bb) = (ushort_t)(w23 >> 16);
        }
    };

    for (int c = 0; c < NCHB; ++c) {
        const int cg = c0 + c;

        // ---------- stage 1 ----------
        do_tile(cg, w);
        do_tile(cg, w + 4);
        if (w == (cg & 3)) do_tile(cg, 8);
        __syncthreads();   // BAR1: CTb complete

        // ---------- stage 2: MFMA, waves split k ----------
        const int rot  = (cg + 1) & 3;               // 3-k wave != 9th-tile wave
        const int idx  = (w - rot) & 3;
        const int kbeg = (idx == 0) ? 0 : (idx == 1) ? 3 : (idx == 2) ? 5 : 7;
        const int kcnt = (idx == 0) ? 3 : 2;
        const int gg   = (lane >> 4) * 16;           // d-group byte offset

        f32x4 acc2 = (f32x4){0.f, 0.f, 0.f, 0.f};
        for (int kk = 0; kk < kcnt; ++kk) {
            int k = kbeg + kk;
            int pbase = ((lane & 15) + k) * PPR + gg;        // A: p[t+k][d]
            int cbase = ((lane & 15) * KS + k) * CTR + gg;   // B: Khi[o*9+k][d]
            #pragma unroll
            for (int dh = 0; dh < 2; ++dh) {
                bf16x8 phi = *(const bf16x8*)(smem + PEPH_OFF + pbase + dh * 64);
                bf16x8 plo = *(const bf16x8*)(smem + PEPL_OFF + pbase + dh * 64);
                bf16x8 khi = *(const bf16x8*)(smem + cbase + dh * 64);
                acc2 = __builtin_amdgcn_mfma_f32_16x16x32_bf16(phi, khi, acc2, 0, 0, 0);
                acc2 = __builtin_amdgcn_mfma_f32_16x16x32_bf16(plo, khi, acc2, 0, 0, 0);
            }
        }
        // D[row=t=(lane>>4)*4+reg, col=o=lane&15] -> atomic accumulate
        {
            int t0 = (lane >> 4) * 4;
            float* ob = out + (size_t)n * (OC * TO) + cg * (CHO * TO) + (lane & 15) * TO;
            #pragma unroll
            for (int r2 = 0; r2 < 4; ++r2) {
                int t = t0 + r2;
                if (t < TO) unsafeAtomicAdd(ob + t, acc2[r2]);
            }
        }
        __syncthreads();   // BAR2: CTb reads done before next stage-1 writes
    }
}

// ---------------- fallback (f32 VALU, known-good) ----------------
__global__ __launch_bounds__(256, 4) void iconv_f32(
    const float* __restrict__ pep, const float* __restrict__ mhc,
    const float* __restrict__ wsrc, const float* __restrict__ bias,
    float* __restrict__ out)
{
    __shared__ float so[4 * 900];
    const int n = blockIdx.x, tid = threadIdx.x, lane = tid & 63;
    const int w = __builtin_amdgcn_readfirstlane(tid >> 6);
    float m[L];
    { const float* mp = mhc + (size_t)n * L * D + lane;
      #pragma unroll
      for (int l = 0; l < L; ++l) m[l] = mp[l * D]; }
    float p[PEP];
    { const float* pp = pep + (size_t)n * PEP * D + lane;
      #pragma unroll
      for (int j = 0; j < PEP; ++j) p[j] = pp[j * D]; }
    for (int oo = 0; oo < OC / 4; ++oo) {
        const int o = w * (OC / 4) + oo;
        float acc[TO];
        #pragma unroll
        for (int t = 0; t < TO; ++t) acc[t] = 0.f;
        #pragma unroll
        for (int k = 0; k < KS; ++k) {
            const float2* wrow = reinterpret_cast<const float2*>(wsrc + (size_t)o * KS * L);
            float wr[L];
            #pragma unroll
            for (int q = 0; q < L / 2; ++q) {
                float2 v = wrow[k * (L / 2) + q];
                wr[q * 2] = v.x; wr[q * 2 + 1] = v.y;
            }
            float k0 = 0.f, k1 = 0.f, k2 = 0.f, k3 = 0.f;
            #pragma unroll
            for (int l = 0; l < 32; l += 4) {
                k0 = fmaf(m[l], wr[l], k0);   k1 = fmaf(m[l + 1], wr[l + 1], k1);
                k2 = fmaf(m[l + 2], wr[l + 2], k2); k3 = fmaf(m[l + 3], wr[l + 3], k3);
            }
            k0 = fmaf(m[32], wr[32], k0); k1 = fmaf(m[33], wr[33], k1);
            float kk = fmaxf((k0 + k2) + (k1 + k3), 0.f);
            #pragma unroll
            for (int t = 0; t < TO; ++t) acc[t] = fmaf(p[t + k], kk, acc[t]);
        }
        #pragma unroll
        for (int t = 0; t < TO; ++t) {
            float a = acc[t];
            a += __shfl_xor(a, 1, 64); a += __shfl_xor(a, 2, 64);
            a += __shfl_xor(a, 4, 64); a += __shfl_xor(a, 8, 64);
            if ((lane & 15) == 0) so[(lane >> 4) * 900 + o * TO + t] = a;
        }
    }
    __syncthreads();
    float* on = out + (size_t)n * OC * TO;
    for (int i = tid; i < OC * TO; i += 256) {
        int o = i / TO;
        on[i] = (so[i] + so[900 + i]) + (so[1800 + i] + so[2700 + i]) + bias[o];
    }
}

extern "C" void kernel_launch(void* const* d_in, const int* in_sizes, int n_in,
                              void* d_out, int out_size, void* d_ws, size_t ws_size,
                              hipStream_t stream) {
    const float* pep  = (const float*)d_in[0];
    const float* mhc  = (const float*)d_in[1];
    const float* W    = (const float*)d_in[2];
    const float* bias = (const float*)d_in[3];
    float* out        = (float*)d_out;
    const int bs = in_sizes[0] / (PEP * D);

    const size_t need = 2 * WP_FRAG * sizeof(ushort_t) + WP_TAILF * sizeof(float); // 294912
    if (d_ws != nullptr && ws_size >= need) {
        ushort_t* wpx = (ushort_t*)d_ws;
        const int tot = 2 * WP_FRAG + WP_TAILF;
        wprep_kernel<<<(tot + 255) / 256, 256, 0, stream>>>(W, wpx);
        const int ototal = bs * OC * TO;
        oinit_kernel<<<(ototal + 255) / 256, 256, 0, stream>>>(bias, out, ototal);
        iconv_mfma<<<dim3(bs, 2), 256, 0, stream>>>(pep, mhc, wpx, out);
    } else {
        iconv_f32<<<bs, 256, 0, stream>>>(pep, mhc, W, bias, out);
    }
}

// Round 12
// 154.931 us; speedup vs baseline: 1.2944x; 1.2944x over previous
//
#include <hip/hip_runtime.h>

typedef __attribute__((ext_vector_type(8))) short bf16x8;
typedef __attribute__((ext_vector_type(4))) float f32x4;
typedef unsigned short ushort_t;
typedef unsigned int uint_t;

constexpr int PEP = 15;   // peptide length
constexpr int D   = 64;   // feature dim
constexpr int L   = 34;   // mhc length (stage-1 contraction)
constexpr int OC  = 128;  // output channels
constexpr int KS  = 9;    // kernel size
constexpr int TO  = 7;    // output positions
constexpr int OK  = OC * KS;      // 1152 stage-1 rows
constexpr int MTG = OK / 16;      // 72 global M-tiles
constexpr int NCHB = 4;           // chunks per block (grid-split 2x)
constexpr int CHO = 16;           // o per chunk
constexpr int MT_CH = 9;          // M-tiles per chunk (144 rows)
// LDS map (51200 B total -> 3 blocks/CU):
//   CTbH [0,20736)        bf16-hi kernel, row=o_local*9+k (144B rows)
//   CTbL [20736,41472)    bf16-lo kernel
//   pepH [41472,43776)    bf16-hi pep, 16 rows x 144B (row 15 = zeros)
//   pepL [43776,46080)    bf16-lo pep
//   pa   [46080,51200)    f32 partials [wave][o*20+t] (16B-aligned stores)
constexpr int CTR = 144;
constexpr int PPR = 144;
constexpr int CTL_OFF  = 20736;
constexpr int PEPH_OFF = 41472;
constexpr int PEPL_OFF = 43776;
constexpr int PA_OFF   = 46080;
constexpr int SMEM_BYTES = 51200;
// wprep layout (294912 B, unchanged):
constexpr int WP_FRAG = 36864;
constexpr int WP_TAILF = 36864;

__device__ __forceinline__ ushort_t f2bf(float v) {
    uint_t u = __float_as_uint(v);
    return (ushort_t)((u + 0x7fffu + ((u >> 16) & 1u)) >> 16);   // RTNE
}
__device__ __forceinline__ float bf2f(ushort_t h) {
    return __uint_as_float(((uint_t)h) << 16);
}
__device__ __forceinline__ uint_t cvt_pk_bf16(float a, float b) {
    uint_t r;
    asm("v_cvt_pk_bf16_f32 %0, %1, %2" : "=v"(r) : "v"(a), "v"(b));
    return r;   // lo16 = bf16(a), hi16 = bf16(b)
}

// Pre-kernel: W -> {hi,lo bf16 frags l=0..31} + {exact f32 tail l=32,33}.
__global__ void wprep_kernel(const float* __restrict__ W, ushort_t* __restrict__ wp) {
    int x = blockIdx.x * 256 + threadIdx.x;
    if (x < 2 * WP_FRAG) {
        int sp = x / WP_FRAG;
        int r  = x % WP_FRAG;
        int i  = r & 7;
        int ln = (r >> 3) & 63;
        int mt = r >> 9;
        int ok = mt * 16 + (ln & 15);
        int l  = (ln >> 4) * 8 + i;
        float v = W[ok * L + l];
        ushort_t hi = f2bf(v);
        wp[x] = sp ? f2bf(v - bf2f(hi)) : hi;
    } else if (x < 2 * WP_FRAG + WP_TAILF) {
        int y  = x - 2 * WP_FRAG;
        int c  = y & 1;
        int j  = (y >> 1) & 3;
        int ln = (y >> 3) & 63;
        int mt = y >> 9;
        int row = mt * 16 + (ln >> 4) * 4 + j;
        ((float*)(wp + 2 * WP_FRAG))[y] = W[row * L + 32 + c];
    }
}

// Grid (bs, 2). Per chunk: stage-1 MFMA -> relu -> CTb hi/lo. BAR1.
// Stage-2 MFMA (A=pep hi/lo, B=CTb hi/lo, 3 products), waves split k
// {3,2,2,2}; per-wave 16x16 f32 partial -> pa (LDS). BAR2. Fold 4 partials
// + bias -> coalesced out store (no atomics, no HBM reduction traffic).
__global__ __launch_bounds__(256, 3) void iconv_mfma(
    const float* __restrict__ pep,
    const float* __restrict__ mhc,
    const ushort_t* __restrict__ wp,
    const float* __restrict__ bias,
    float* __restrict__ out)
{
    __shared__ __align__(16) char smem[SMEM_BYTES];
    const int n    = blockIdx.x;
    const int c0   = blockIdx.y * NCHB;
    const int tid  = threadIdx.x;
    const int lane = tid & 63;
    const int w    = tid >> 6;

    // m rows 32,33 exact f32 (stage-1 K-tail), per nt
    float m32v[4], m33v[4];
    {
        const float* mb = mhc + (size_t)n * L * D;
        #pragma unroll
        for (int nt = 0; nt < 4; ++nt) {
            int d = (lane & 15) + 16 * nt;
            m32v[nt] = mb[32 * D + d];
            m33v[nt] = mb[33 * D + d];
        }
    }

    // Prologue A: m^T (l=0..31) hi/lo bf16, XOR-swizzled, at [0,16384) (one-time;
    // aliases CTb region, dead after B-frag load below)
    {
        const float* mp = mhc + (size_t)n * L * D + lane;
        #pragma unroll
        for (int j = 0; j < 8; ++j) {
            int l = w + 4 * j;
            float v = mp[l * D];
            ushort_t hi = f2bf(v);
            ushort_t lo = f2bf(v - bf2f(hi));
            int byte = (lane * 128 + l * 2) ^ ((lane & 7) << 4);
            *(ushort_t*)(smem + byte)        = hi;
            *(ushort_t*)(smem + 8192 + byte) = lo;
        }
    }
    // Prologue B: pep rows 0..15 hi/lo bf16 planes (row 15 zeroed: r<PEP guard)
    {
        const float* pp = pep + (size_t)n * PEP * D + lane;
        #pragma unroll
        for (int j = 0; j < 4; ++j) {
            int r = w + 4 * j;
            float v = (r < PEP) ? pp[r * D] : 0.0f;
            ushort_t hi = f2bf(v);
            ushort_t lo = f2bf(v - bf2f(hi));
            int byte = r * PPR + lane * 2;
            *(ushort_t*)(smem + PEPH_OFF + byte) = hi;
            *(ushort_t*)(smem + PEPL_OFF + byte) = lo;
        }
    }
    __syncthreads();

    // stage-1 B-fragments (m): [nt][hi/lo]
    bf16x8 bf[4][2];
    #pragma unroll
    for (int nt = 0; nt < 4; ++nt) {
        int d = (lane & 15) + 16 * nt;
        int l0 = (lane >> 4) * 8;
        int byte = (d * 128 + l0 * 2) ^ ((d & 7) << 4);
        bf[nt][0] = *(const bf16x8*)(smem + byte);
        bf[nt][1] = *(const bf16x8*)(smem + 8192 + byte);
    }
    __syncthreads();   // mT dead; CTb may overwrite

    const float* wtail = (const float*)(wp + 2 * WP_FRAG);

    auto do_tile = [&](int cg, int mtl) {
        int mtG = cg * MT_CH + mtl;
        const ushort_t* base = wp + mtG * 512 + lane * 8;
        bf16x8 ah = *(const bf16x8*)(base);
        bf16x8 al = *(const bf16x8*)(base + WP_FRAG);
        const float4* tb = (const float4*)(wtail + (size_t)(mtG * 64 + lane) * 8);
        float4 ft0 = tb[0];
        float4 ft1 = tb[1];

        f32x4 acc[4];
        #pragma unroll
        for (int nt = 0; nt < 4; ++nt) acc[nt] = (f32x4){0.f, 0.f, 0.f, 0.f};
        #pragma unroll
        for (int nt = 0; nt < 4; ++nt) {
            acc[nt] = __builtin_amdgcn_mfma_f32_16x16x32_bf16(ah, bf[nt][0], acc[nt], 0, 0, 0);
            acc[nt] = __builtin_amdgcn_mfma_f32_16x16x32_bf16(ah, bf[nt][1], acc[nt], 0, 0, 0);
            acc[nt] = __builtin_amdgcn_mfma_f32_16x16x32_bf16(al, bf[nt][0], acc[nt], 0, 0, 0);
        }
        #pragma unroll
        for (int nt = 0; nt < 4; ++nt) {   // exact K-tail l=32,33
            acc[nt][0] = fmaf(ft0.x, m32v[nt], fmaf(ft0.y, m33v[nt], acc[nt][0]));
            acc[nt][1] = fmaf(ft0.z, m32v[nt], fmaf(ft0.w, m33v[nt], acc[nt][1]));
            acc[nt][2] = fmaf(ft1.x, m32v[nt], fmaf(ft1.y, m33v[nt], acc[nt][2]));
            acc[nt][3] = fmaf(ft1.z, m32v[nt], fmaf(ft1.w, m33v[nt], acc[nt][3]));
        }

        int r0 = mtl * 16 + (lane >> 4) * 4;
        #pragma unroll
        for (int nt = 0; nt < 4; ++nt) {   // relu -> bf16 hi+lo -> CTbH/CTbL
            int bb = ((lane & 15) + 16 * nt) * 2;
            float v0 = fmaxf(acc[nt][0], 0.f), v1 = fmaxf(acc[nt][1], 0.f);
            float v2 = fmaxf(acc[nt][2], 0.f), v3 = fmaxf(acc[nt][3], 0.f);
            uint_t h01 = cvt_pk_bf16(v0, v1);
            uint_t h23 = cvt_pk_bf16(v2, v3);
            float r0f = v0 - __uint_as_float(h01 << 16);
            float r1f = v1 - __uint_as_float(h01 & 0xffff0000u);
            float r2f = v2 - __uint_as_float(h23 << 16);
            float r3f = v3 - __uint_as_float(h23 & 0xffff0000u);
            uint_t l01 = cvt_pk_bf16(r0f, r1f);
            uint_t l23 = cvt_pk_bf16(r2f, r3f);
            *(ushort_t*)(smem + (r0 + 0) * CTR + bb) = (ushort_t)(h01 & 0xffffu);
            *(ushort_t*)(smem + (r0 + 1) * CTR + bb) = (ushort_t)(h01 >> 16);
            *(ushort_t*)(smem + (r0 + 2) * CTR + bb) = (ushort_t)(h23 & 0xffffu);
            *(ushort_t*)(smem + (r0 + 3) * CTR + bb) = (ushort_t)(h23 >> 16);
            *(ushort_t*)(smem + CTL_OFF + (r0 + 0) * CTR + bb) = (ushort_t)(l01 & 0xffffu);
            *(ushort_t*)(smem + CTL_OFF + (r0 + 1) * CTR + bb) = (ushort_t)(l01 >> 16);
            *(ushort_t*)(smem + CTL_OFF + (r0 + 2) * CTR + bb) = (ushort_t)(l23 & 0xffffu);
            *(ushort_t*)(smem + CTL_OFF + (r0 + 3) * CTR + bb) = (ushort_t)(l23 >> 16);
        }
    };

    for (int c = 0; c < NCHB; ++c) {
        const int cg = c0 + c;

        // ---------- stage 1 ----------
        do_tile(cg, w);
        do_tile(cg, w + 4);
        if (w == (cg & 3)) do_tile(cg, 8);
        __syncthreads();   // BAR1: CTb complete

        // ---------- stage 2: MFMA, waves split k {3,2,2,2} ----------
        const int rot  = (cg + 1) & 3;               // 3-k wave != 9th-tile wave
        const int idx  = (w - rot) & 3;
        const int kbeg = (idx == 0) ? 0 : (idx == 1) ? 3 : (idx == 2) ? 5 : 7;
        const int kcnt = (idx == 0) ? 3 : 2;
        const int gg   = (lane >> 4) * 16;           // d-group byte offset

        f32x4 acc2 = (f32x4){0.f, 0.f, 0.f, 0.f};
        for (int kk = 0; kk < kcnt; ++kk) {
            int k = kbeg + kk;
            int pr = (lane & 15) + k;                // pep row; >=15 -> zero row
            if (pr > 15) pr = 15;
            int pbase = pr * PPR + gg;
            int cbase = ((lane & 15) * KS + k) * CTR + gg;
            #pragma unroll
            for (int dh = 0; dh < 2; ++dh) {
                bf16x8 phi = *(const bf16x8*)(smem + PEPH_OFF + pbase + dh * 64);
                bf16x8 plo = *(const bf16x8*)(smem + PEPL_OFF + pbase + dh * 64);
                bf16x8 khi = *(const bf16x8*)(smem + cbase + dh * 64);
                bf16x8 klo = *(const bf16x8*)(smem + CTL_OFF + cbase + dh * 64);
                acc2 = __builtin_amdgcn_mfma_f32_16x16x32_bf16(phi, khi, acc2, 0, 0, 0);
                acc2 = __builtin_amdgcn_mfma_f32_16x16x32_bf16(plo, khi, acc2, 0, 0, 0);
                acc2 = __builtin_amdgcn_mfma_f32_16x16x32_bf16(phi, klo, acc2, 0, 0, 0);
            }
        }
        // partial tile -> pa[w][o*20 + t0..t0+3] (16B-aligned b128 store)
        {
            int off = PA_OFF + (w * 320 + (lane & 15) * 20 + (lane >> 4) * 4) * 4;
            *(f32x4*)(smem + off) = acc2;
        }
        __syncthreads();   // BAR2: pa complete; CTb reads complete

        // fold: 112 threads sum 4 partials + bias -> coalesced out store
        if (tid < CHO * TO) {
            int o_l = tid / TO;
            int t   = tid % TO;
            const float* pa = (const float*)(smem + PA_OFF);
            int e = o_l * 20 + t;
            float v = (pa[e] + pa[320 + e]) + (pa[640 + e] + pa[960 + e]);
            out[(size_t)n * (OC * TO) + (cg * CHO + o_l) * TO + t] =
                v + bias[cg * CHO + o_l];
        }
        // next stage-1 writes CTb only (pa/pep disjoint); next pa-write is
        // after next BAR1, ordering it against these pa-reads.
    }
}

// ---------------- fallback (f32 VALU, known-good) ----------------
__global__ __launch_bounds__(256, 4) void iconv_f32(
    const float* __restrict__ pep, const float* __restrict__ mhc,
    const float* __restrict__ wsrc, const float* __restrict__ bias,
    float* __restrict__ out)
{
    __shared__ float so[4 * 900];
    const int n = blockIdx.x, tid = threadIdx.x, lane = tid & 63;
    const int w = __builtin_amdgcn_readfirstlane(tid >> 6);
    float m[L];
    { const float* mp = mhc + (size_t)n * L * D + lane;
      #pragma unroll
      for (int l = 0; l < L; ++l) m[l] = mp[l * D]; }
    float p[PEP];
    { const float* pp = pep + (size_t)n * PEP * D + lane;
      #pragma unroll
      for (int j = 0; j < PEP; ++j) p[j] = pp[j * D]; }
    for (int oo = 0; oo < OC / 4; ++oo) {
        const int o = w * (OC / 4) + oo;
        float acc[TO];
        #pragma unroll
        for (int t = 0; t < TO; ++t) acc[t] = 0.f;
        #pragma unroll
        for (int k = 0; k < KS; ++k) {
            const float2* wrow = reinterpret_cast<const float2*>(wsrc + (size_t)o * KS * L);
            float wr[L];
            #pragma unroll
            for (int q = 0; q < L / 2; ++q) {
                float2 v = wrow[k * (L / 2) + q];
                wr[q * 2] = v.x; wr[q * 2 + 1] = v.y;
            }
            float k0 = 0.f, k1 = 0.f, k2 = 0.f, k3 = 0.f;
            #pragma unroll
            for (int l = 0; l < 32; l += 4) {
                k0 = fmaf(m[l], wr[l], k0);   k1 = fmaf(m[l + 1], wr[l + 1], k1);
                k2 = fmaf(m[l + 2], wr[l + 2], k2); k3 = fmaf(m[l + 3], wr[l + 3], k3);
            }
            k0 = fmaf(m[32], wr[32], k0); k1 = fmaf(m[33], wr[33], k1);
            float kk = fmaxf((k0 + k2) + (k1 + k3), 0.f);
            #pragma unroll
            for (int t = 0; t < TO; ++t) acc[t] = fmaf(p[t + k], kk, acc[t]);
        }
        #pragma unroll
        for (int t = 0; t < TO; ++t) {
            float a = acc[t];
            a += __shfl_xor(a, 1, 64); a += __shfl_xor(a, 2, 64);
            a += __shfl_xor(a, 4, 64); a += __shfl_xor(a, 8, 64);
            if ((lane & 15) == 0) so[(lane >> 4) * 900 + o * TO + t] = a;
        }
    }
    __syncthreads();
    float* on = out + (size_t)n * OC * TO;
    for (int i = tid; i < OC * TO; i += 256) {
        int o = i / TO;
        on[i] = (so[i] + so[900 + i]) + (so[1800 + i] + so[2700 + i]) + bias[o];
    }
}

extern "C" void kernel_launch(void* const* d_in, const int* in_sizes, int n_in,
                              void* d_out, int out_size, void* d_ws, size_t ws_size,
                              hipStream_t stream) {
    const float* pep  = (const float*)d_in[0];
    const float* mhc  = (const float*)d_in[1];
    const float* W    = (const float*)d_in[2];
    const float* bias = (const float*)d_in[3];
    float* out        = (float*)d_out;
    const int bs = in_sizes[0] / (PEP * D);

    const size_t need = 2 * WP_FRAG * sizeof(ushort_t) + WP_TAILF * sizeof(float); // 294912
    if (d_ws != nullptr && ws_size >= need) {
        ushort_t* wpx = (ushort_t*)d_ws;
        const int tot = 2 * WP_FRAG + WP_TAILF;
        wprep_kernel<<<(tot + 255) / 256, 256, 0, stream>>>(W, wpx);
        iconv_mfma<<<dim3(bs, 2), 256, 0, stream>>>(pep, mhc, wpx, bias, out);
    } else {
        iconv_f32<<<bs, 256, 0, stream>>>(pep, mhc, W, bias, out);
    }
}